// Round 5
// baseline (298.687 us; speedup 1.0000x reference)
//
#include <hip/hip_runtime.h>

namespace {

constexpr int T = 32, H = 56, W = 56;
constexpr int HW = H * W;            // 3136
constexpr int THW = T * HW;
constexpr int PAIRS = HW / 2;        // 1568 pixel-pairs per (b,c) plane
constexpr int BLK = 128;
constexpr int BPB = (PAIRS + BLK - 1) / BLK;   // 13 blocks per (b,c)

// Tiny structs with NO array indexing anywhere -> SROA is guaranteed; the
// R1/R2 kernels died because cc[7][3][4] (84-117 live floats) got demoted to
// scratch (~100 MB/dispatch of spill traffic, VGPR_Count=64 in R2).
struct F2 { float x, y; };
struct R4 { float c0, c1, c2, c3; };

__device__ __forceinline__ F2 f2(float v) { F2 r; r.x = v; r.y = v; return r; }

__device__ __forceinline__ float sigm(float v) {
    // 1/(1+e^-v): fast exp+rcp, rel err ~1e-6 vs 1.9e-2 threshold
    return __builtin_amdgcn_rcpf(1.0f + __expf(-v));
}

// One 3x3 spatial kernel applied to the 3x4 transient window, 2 px/thread.
__device__ __forceinline__ void acc9(F2& a, const R4& r0, const R4& r1, const R4& r2,
                                     const float* __restrict__ w9) {
    const float k00 = w9[0], k01 = w9[1], k02 = w9[2];
    const float k10 = w9[3], k11 = w9[4], k12 = w9[5];
    const float k20 = w9[6], k21 = w9[7], k22 = w9[8];
    a.x = fmaf(r0.c0, k00, fmaf(r0.c1, k01, fmaf(r0.c2, k02, a.x)));
    a.y = fmaf(r0.c1, k00, fmaf(r0.c2, k01, fmaf(r0.c3, k02, a.y)));
    a.x = fmaf(r1.c0, k10, fmaf(r1.c1, k11, fmaf(r1.c2, k12, a.x)));
    a.y = fmaf(r1.c1, k10, fmaf(r1.c2, k11, fmaf(r1.c3, k12, a.y)));
    a.x = fmaf(r2.c0, k20, fmaf(r2.c1, k21, fmaf(r2.c2, k22, a.x)));
    a.y = fmaf(r2.c1, k20, fmaf(r2.c2, k21, fmaf(r2.c3, k22, a.y)));
}

__device__ __forceinline__ R4 load_row(const float* __restrict__ p, bool vrow,
                                       bool vl, bool vr, int cl, int cr) {
    R4 r;
    const float2 m = *(const float2*)p;   // 8B aligned: w0, W, HW all even
    const float e0 = p[cl];               // clamped addr, always in-bounds
    const float e3 = p[cr];               // cr=0 when !vr: discarded below
    r.c0 = (vrow && vl) ? e0  : 0.f;
    r.c1 = vrow         ? m.x : 0.f;
    r.c2 = vrow         ? m.y : 0.f;
    r.c3 = (vrow && vr) ? e3  : 0.f;
    return r;
}

__global__ __launch_bounds__(BLK, 4)   // cap VGPR at 128 -> 4 waves/SIMD
void tts_fused(const float* __restrict__ x,
               const float* __restrict__ w1, const float* __restrict__ b1,
               const float* __restrict__ w2, const float* __restrict__ b2,
               const float* __restrict__ w3, const float* __restrict__ b3,
               const float* __restrict__ wm,
               float* __restrict__ out) {
    const int bid = blockIdx.x;
    const int bc  = bid / BPB;                 // b*64 + c (uniform per block)
    const int sub = bid - bc * BPB;
    const int q   = sub * BLK + threadIdx.x;   // pair index in plane
    if (q >= PAIRS) return;                    // no barriers -> safe early exit
    const int px0 = q * 2;
    const int h   = px0 / W;
    const int w0  = px0 - h * W;               // even

    const float* __restrict__ xb = x + (size_t)bc * THW;
    float* __restrict__ ob       = out + (size_t)bc * THW;
    const int c = bc & 63;
    const float* __restrict__ wa = w1 + c * 27;  // [kt*9 + kh*3 + kw]
    const float* __restrict__ wb = w2 + c * 27;
    const float* __restrict__ wc = w3 + c * 27;
    const float bias1 = b1[c], bias2 = b2[c], bias3 = b3[c];
    const float W0 = wm[0], W1 = wm[1], W2 = wm[2];
    const float goff = 0.5f * (W0 + W1 + W2);

    const bool vt = (h > 0), vbm = (h < H - 1);
    const bool vl = (w0 > 0), vr = (w0 < W - 2);
    const int base = h * W + w0;
    const int ro0 = vt  ? -W : 0;   // clamped row offsets (always valid mem)
    const int ro2 = vbm ?  W : 0;
    const int cl  = vl ? -1 : 0;    // clamped col-edge offsets
    // BUGFIX R4: was `vr ? 3 : 0` — p[3] is x(w0+3), ONE COLUMN TOO FAR; the
    // window is w0-1..w0+2 so the right edge is p[2] (R2's passing kernel used
    // rp[2]). This off-by-one also explains R3's crash: its !vr "clamp" p[2]
    // crossed the row end at the last pixel of the buffer. p[2] with vr
    // (w0<=52) is always inside the row; p[0] when !vr is discarded.
    const int cr  = vr ? 2 : 0;

    // pending conv accumulators: a1_i = conv1(s-1+i), a2_i = conv2(s-2+i),
    // a3_i = conv3(s-3+i) at the top of step s. Init = bias (zero temporal pad).
    F2 a1_0 = f2(bias1), a1_1 = f2(bias1), a1_2 = f2(bias1);
    F2 a2_0 = f2(bias2), a2_1 = f2(bias2), a2_2 = f2(bias2), a2_3 = f2(bias2),
       a2_4 = f2(bias2);
    F2 a3_0 = f2(bias3), a3_1 = f2(bias3), a3_2 = f2(bias3), a3_3 = f2(bias3),
       a3_4 = f2(bias3), a3_5 = f2(bias3), a3_6 = f2(bias3);
    // lag-diff previous finalized conv values
    F2 c1p = f2(0.f), c2p1 = f2(0.f), c2p2 = f2(0.f);
    F2 c3p1 = f2(0.f), c3p2 = f2(0.f), c3p3 = f2(0.f);
    // gate partials: gM = partial(t=s-2) {s1}, gO = partial(t=s-3) {s1+s2}
    F2 gM = f2(0.f), gO = f2(0.f);
    // x-center history: xc1 = x(s-1), xc2 = x(s-2), xc3 = x(s-3)
    F2 xc1 = f2(0.f), xc2 = f2(0.f), xc3 = f2(0.f);

    int poff = base;
    int ooff = base;

#pragma unroll 1
    for (int s = 0; s < T + 3; ++s) {
        // 1. transient plane s (3 rows x 4 cols), zero past the end
        R4 r0, r1, r2;
        if (s < T) {
            const float* ps = xb + poff;
            r0 = load_row(ps + ro0, vt,   vl, vr, cl, cr);
            r1 = load_row(ps,       true, vl, vr, cl, cr);
            r2 = load_row(ps + ro2, vbm,  vl, vr, cl, cr);
            poff += HW;
        } else {
            r0.c0 = r0.c1 = r0.c2 = r0.c3 = 0.f;
            r1 = r0; r2 = r0;
        }

        // 2. scatter plane s into the 9 pending 2D-conv targets
        acc9(a1_2, r0, r1, r2, wa);      // -> conv1(s+1), kt=0
        acc9(a1_1, r0, r1, r2, wa + 9);  // -> conv1(s),   kt=1
        acc9(a1_0, r0, r1, r2, wa + 18); // -> conv1(s-1), kt=2 (finalizes)
        acc9(a2_4, r0, r1, r2, wb);      // -> conv2(s+2)
        acc9(a2_2, r0, r1, r2, wb + 9);  // -> conv2(s)
        acc9(a2_0, r0, r1, r2, wb + 18); // -> conv2(s-2) (finalizes)
        acc9(a3_6, r0, r1, r2, wc);      // -> conv3(s+3)
        acc9(a3_3, r0, r1, r2, wc + 9);  // -> conv3(s)
        acc9(a3_0, r0, r1, r2, wc + 18); // -> conv3(s-3) (finalizes)

        // 3. finalize c1(s-1), c2(s-2), c3(s-3); lag-diff with keep-first-k
        const F2 c1 = a1_0, c2 = a2_0, c3 = a3_0;
        F2 d1, d2, d3;
        if (s >= 2) { d1.x = c1.x - c1p.x;  d1.y = c1.y - c1p.y;  } else d1 = c1;
        if (s >= 4) { d2.x = c2.x - c2p2.x; d2.y = c2.y - c2p2.y; } else d2 = c2;
        if (s >= 6) { d3.x = c3.x - c3p3.x; d3.y = c3.y - c3p3.y; } else d3 = c3;

        F2 s1v, s2v, s3v;
        s1v.x = sigm(d1.x) * W0; s1v.y = sigm(d1.y) * W0;
        s2v.x = sigm(d2.x) * W1; s2v.y = sigm(d2.y) * W1;
        s3v.x = sigm(d3.x) * W2; s3v.y = sigm(d3.y) * W2;

        // 4. gate(t=s-3) completes -> emit out(t)
        if (s >= 3) {
            float2 ov;
            ov.x = xc3.x * (gO.x + s3v.x - goff);
            ov.y = xc3.y * (gO.y + s3v.y - goff);
            *(float2*)(ob + ooff) = ov;
            ooff += HW;
        }
        gO.x = gM.x + s2v.x; gO.y = gM.y + s2v.y;
        gM = s1v;

        // 5. shift pending-acc rings, refill with bias
        a1_0 = a1_1; a1_1 = a1_2; a1_2 = f2(bias1);
        a2_0 = a2_1; a2_1 = a2_2; a2_2 = a2_3; a2_3 = a2_4; a2_4 = f2(bias2);
        a3_0 = a3_1; a3_1 = a3_2; a3_2 = a3_3; a3_3 = a3_4; a3_4 = a3_5;
        a3_5 = a3_6; a3_6 = f2(bias3);

        // 6. lag chains
        c1p = c1;
        c2p2 = c2p1; c2p1 = c2;
        c3p3 = c3p2; c3p2 = c3p1; c3p1 = c3;

        // 7. x-center history (plane s center = r1.c1, r1.c2)
        xc3 = xc2; xc2 = xc1;
        xc1.x = r1.c1; xc1.y = r1.c2;
    }
}

}  // namespace

extern "C" void kernel_launch(void* const* d_in, const int* in_sizes, int n_in,
                              void* d_out, int out_size, void* d_ws, size_t ws_size,
                              hipStream_t stream) {
    (void)in_sizes; (void)n_in; (void)d_ws; (void)ws_size; (void)out_size;
    const float* x  = (const float*)d_in[0];
    const float* w1 = (const float*)d_in[1];
    const float* b1 = (const float*)d_in[2];
    const float* w2 = (const float*)d_in[3];
    const float* b2 = (const float*)d_in[4];
    const float* w3 = (const float*)d_in[5];
    const float* b3 = (const float*)d_in[6];
    const float* wm = (const float*)d_in[7];
    float* out = (float*)d_out;

    // 256 (b,c) x 13 pair-blocks; 128 threads x 2 px each
    tts_fused<<<dim3(256 * BPB), dim3(BLK), 0, stream>>>(
        x, w1, b1, w2, b2, w3, b3, wm, out);
}